// Round 2
// baseline (14.485 us; speedup 1.0000x reference)
//
#include <hip/hip_runtime.h>
#include <math.h>

#define NUM_CLASSES 4
#define EPS 1e-7f
#define B_ 64
#define T_ 50
#define NNEG 500
#define NPOSB 38                 // 38*256 = 9728 >= 9600 positives
#define NNEGB 375                // 375*256 = 96000 negatives exactly
#define NBLK (NPOSB + NNEGB)     // 413 blocks total
#define MAGIC 0x13579BDFu        // != 0xAAAAAAAA (poison), != 0 (post-run state)
#define WSTRIDE 8                // floats per block slot in ws (5 partials + flag + pad)

__device__ __forceinline__ float softplusf(float x) {
    // matches jax.nn.softplus = logaddexp(x, 0)
    return fmaxf(x, 0.0f) + log1pf(expf(-fabsf(x)));
}

// ws slot i: [box, cls, conf, n, neg, flag(u32), pad, pad]
__global__ void __launch_bounds__(256) yolo_fused(
        const float* __restrict__ pr3, const float* __restrict__ pr4,
        const float* __restrict__ pr5, const float* __restrict__ targets,
        const float* __restrict__ anchors,
        const int* __restrict__ ng3, const int* __restrict__ ng4,
        const int* __restrict__ ng5, float* __restrict__ ws,
        float* __restrict__ out) {
    __shared__ float sred[5][256];

    const int bid = blockIdx.x;
    const int tid = threadIdx.x;

    float v0 = 0.f, v1 = 0.f, v2 = 0.f, v3 = 0.f, v4 = 0.f; // box, cls, conf, n, neg

    if (bid < NPOSB) {
        // ---------------- positive targets: 3 scales * 64 * 50 = 9600 ----
        int idx = bid * 256 + tid;
        if (idx < 3 * B_ * T_) {
            int s   = idx / (B_ * T_);
            int rem = idx - s * (B_ * T_);
            int b   = rem / T_;
            int t   = rem - b * T_;

            int hw = (s == 0) ? 80 : ((s == 1) ? 40 : 20);
            const float* pred = (s == 0) ? pr3 : ((s == 1) ? pr4 : pr5);
            int a0 = 3 * s;

            const float* tg = targets + (size_t)(b * T_ + t) * 5;
            float clsf = tg[0], tx = tg[1], ty = tg[2], tw = tg[3], th = tg[4];

            bool valid = (tx >= 0.f) && (tx <= 1.f) && (ty >= 0.f) && (ty <= 1.f) &&
                         (tw > 0.f)  && (tw <= 1.f) && (th > 0.f)  && (th <= 1.f);

            // best-anchor argmax (first max wins, like jnp.argmax)
            int best = 0; float bestv = -1.f, awb = 0.f, ahb = 0.f;
            #pragma unroll
            for (int a = 0; a < 3; ++a) {
                float aw = anchors[(a0 + a) * 2 + 0] / 640.0f;
                float ah = anchors[(a0 + a) * 2 + 1] / 640.0f;
                float inter = fminf(tw, aw) * fminf(th, ah);
                float uni   = tw * th + aw * ah - inter;
                float r     = inter / (uni + EPS);
                if (r > bestv) { bestv = r; best = a; awb = aw; ahb = ah; }
            }

            int w = hw, h = hw;
            int gxi = (int)floorf(tx * (float)w); gxi = min(max(gxi, 0), w - 1);
            int gyi = (int)floorf(ty * (float)h); gyi = min(max(gyi, 0), h - 1);

            size_t chs = (size_t)h * (size_t)w;
            const float* base = pred + ((size_t)(b * 27 + best * 9) * (size_t)h + (size_t)gyi) * (size_t)w + (size_t)gxi;
            float c0 = base[0 * chs], c1 = base[1 * chs], c2 = base[2 * chs];
            float c3 = base[3 * chs], zc = base[4 * chs];
            float z0 = base[5 * chs], z1 = base[6 * chs];
            float z2 = base[7 * chs], z3 = base[8 * chs];

            float px  = 1.f / (1.f + expf(-c0)) + (float)gxi / (float)w;
            float py  = 1.f / (1.f + expf(-c1)) + (float)gyi / (float)h;
            float pw_ = expf(c2) * awb;
            float ph_ = expf(c3) * ahb;

            // GIoU
            float x1n = px - pw_ * 0.5f, x1x = px + pw_ * 0.5f;
            float y1n = py - ph_ * 0.5f, y1x = py + ph_ * 0.5f;
            float x2n = tx - tw * 0.5f,  x2x = tx + tw * 0.5f;
            float y2n = ty - th * 0.5f,  y2x = ty + th * 0.5f;
            float iw = fmaxf(fminf(x1x, x2x) - fmaxf(x1n, x2n), 0.f);
            float ih = fmaxf(fminf(y1x, y2x) - fmaxf(y1n, y2n), 0.f);
            float inter = iw * ih;
            float uni = pw_ * ph_ + tw * th - inter + EPS;
            float iou = inter / uni;
            float ew = fmaxf(x1x, x2x) - fminf(x1n, x2n);
            float eh = fmaxf(y1x, y2x) - fminf(y1n, y2n);
            float enclose = ew * eh + EPS;
            float giou = iou - (enclose - uni) / enclose;

            int cid = (int)clsf;
            float mask = (valid && (cid < NUM_CLASSES)) ? 1.f : 0.f;

            v0 = mask * (1.f - giou);

            float sbce = softplusf(z0) + softplusf(z1) + softplusf(z2) + softplusf(z3);
            float zsel = (cid == 0) ? z0 : (cid == 1) ? z1 : (cid == 2) ? z2 : (cid == 3) ? z3 : 0.f;
            v1 = mask * 0.25f * (sbce - zsel);

            float conf_t = fminf(fmaxf(giou, 0.f), 1.f);
            v2 = mask * (softplusf(zc) - conf_t * zc);

            v3 = valid ? 1.f : 0.f;
        }
    } else {
        // ---------------- negative conf: one element per thread ---------
        int i = (bid - NPOSB) * 256 + tid;   // [0, 96000)
        int s   = i / (B_ * NNEG);
        int rem = i - s * (B_ * NNEG);
        int b   = rem / NNEG;
        int j   = rem - b * NNEG;

        int hw = (s == 0) ? 80 : ((s == 1) ? 40 : 20);
        int chs = hw * hw;
        const float* pred = (s == 0) ? pr3 : ((s == 1) ? pr4 : pr5);
        const int* nix = (s == 0) ? ng3 : ((s == 1) ? ng4 : ng5);

        int id = nix[b * NNEG + j];          // in [0, 3*h*w)
        int a   = id / chs;
        int pos = id - a * chs;
        float z = pred[(size_t)(b * 27 + a * 9 + 4) * (size_t)chs + (size_t)pos];
        v4 = softplusf(z);
    }

    // -------- per-block tree reduce of the 5 partials (deterministic) ----
    sred[0][tid] = v0; sred[1][tid] = v1; sred[2][tid] = v2;
    sred[3][tid] = v3; sred[4][tid] = v4;
    __syncthreads();
    for (int s = 128; s > 0; s >>= 1) {
        if (tid < s) {
            sred[0][tid] += sred[0][tid + s];
            sred[1][tid] += sred[1][tid + s];
            sred[2][tid] += sred[2][tid + s];
            sred[3][tid] += sred[3][tid + s];
            sred[4][tid] += sred[4][tid + s];
        }
        __syncthreads();
    }
    if (tid == 0) {
        float* slot = ws + (size_t)bid * WSTRIDE;
        slot[0] = sred[0][0]; slot[1] = sred[1][0]; slot[2] = sred[2][0];
        slot[3] = sred[3][0]; slot[4] = sred[4][0];
        __hip_atomic_store((unsigned int*)(slot + 5), MAGIC,
                           __ATOMIC_RELEASE, __HIP_MEMORY_SCOPE_AGENT);
    }

    if (bid != 0) return;

    // -------- block 0: spin-acquire all partials, finalize ---------------
    // Safe: 413 blocks fit co-resident (<< 2048 slots) and workers never
    // wait on anything -> no circular dependency even if they weren't.
    float a0 = 0.f, a1 = 0.f, a2 = 0.f, a3 = 0.f, a4 = 0.f;
    #pragma unroll
    for (int half = 0; half < 2; ++half) {
        int i = tid + half * 256;
        if (i < NBLK) {
            unsigned int* flag = (unsigned int*)(ws + (size_t)i * WSTRIDE + 5);
            while (__hip_atomic_load(flag, __ATOMIC_ACQUIRE,
                                     __HIP_MEMORY_SCOPE_AGENT) != MAGIC) {
                __builtin_amdgcn_s_sleep(1);
            }
            const float* slot = ws + (size_t)i * WSTRIDE;
            a0 += slot[0]; a1 += slot[1]; a2 += slot[2];
            a3 += slot[3]; a4 += slot[4];
            *flag = 0u;   // reset for next replay (0 != MAGIC, overwritten next call)
        }
    }
    __syncthreads();   // sred free for reuse after this
    sred[0][tid] = a0; sred[1][tid] = a1; sred[2][tid] = a2;
    sred[3][tid] = a3; sred[4][tid] = a4;
    __syncthreads();
    for (int s = 128; s > 0; s >>= 1) {
        if (tid < s) {
            sred[0][tid] += sred[0][tid + s];
            sred[1][tid] += sred[1][tid + s];
            sred[2][tid] += sred[2][tid + s];
            sred[3][tid] += sred[3][tid + s];
            sred[4][tid] += sred[4][tid + s];
        }
        __syncthreads();
    }
    if (tid == 0) {
        float box = sred[0][0], cls = sred[1][0], conf = sred[2][0];
        float nn = sred[3][0], negsum = sred[4][0];
        float denom = fmaxf(nn, 1.f);
        if (nn > 0.f) { box /= denom; cls /= denom; conf /= denom; }
        // per scale: 0.5 * sum_b(mean_j softplus) / (B*NNEG); same factor
        // for all 3 scales -> folded.
        float neg = 0.5f * negsum / ((float)NNEG * (float)(B_ * NNEG));
        conf += neg;
        out[0] = box + cls + conf; out[1] = box; out[2] = cls; out[3] = conf;
    }
}

extern "C" void kernel_launch(void* const* d_in, const int* in_sizes, int n_in,
                              void* d_out, int out_size, void* d_ws, size_t ws_size,
                              hipStream_t stream) {
    const float* p3      = (const float*)d_in[0];
    const float* p4      = (const float*)d_in[1];
    const float* p5      = (const float*)d_in[2];
    const float* targets = (const float*)d_in[3];
    const float* anchors = (const float*)d_in[4];
    const int*   ng3     = (const int*)d_in[5];
    const int*   ng4     = (const int*)d_in[6];
    const int*   ng5     = (const int*)d_in[7];

    yolo_fused<<<dim3(NBLK), dim3(256), 0, stream>>>(
        p3, p4, p5, targets, anchors, ng3, ng4, ng5,
        (float*)d_ws, (float*)d_out);
}

// Round 3
// 12.766 us; speedup vs baseline: 1.1346x; 1.1346x over previous
//
#include <hip/hip_runtime.h>
#include <math.h>

#define NUM_CLASSES 4
#define EPS 1e-7f
#define B_ 64
#define T_ 50
#define NNEG 500
#define NPOSB 38                 // 38*256 = 9728 >= 9600 positives
#define NNEGB 94                 // 94*256 = 24064 >= 24000 threads (4 negs each)
#define NBLK (NPOSB + NNEGB)     // 132 blocks total
#define MAGIC 0x13579BDFu        // != 0xAAAAAAAA (poison), != 0 (post-run state)
#define WSTRIDE 8                // floats per block slot in ws (5 partials + flag + pad)

__device__ __forceinline__ float softplusf(float x) {
    // matches jax.nn.softplus = logaddexp(x, 0)
    return fmaxf(x, 0.0f) + log1pf(expf(-fabsf(x)));
}

// ws slot i: [box, cls, conf, n, neg, flag(u32), pad, pad]
__global__ void __launch_bounds__(256) yolo_fused(
        const float* __restrict__ pr3, const float* __restrict__ pr4,
        const float* __restrict__ pr5, const float* __restrict__ targets,
        const float* __restrict__ anchors,
        const int* __restrict__ ng3, const int* __restrict__ ng4,
        const int* __restrict__ ng5, float* __restrict__ ws,
        float* __restrict__ out) {
    __shared__ float sred[5][256];

    const int bid = blockIdx.x;
    const int tid = threadIdx.x;

    float v0 = 0.f, v1 = 0.f, v2 = 0.f, v3 = 0.f, v4 = 0.f; // box, cls, conf, n, neg

    if (bid < NPOSB) {
        // ---------------- positive targets: 3 scales * 64 * 50 = 9600 ----
        int idx = bid * 256 + tid;
        if (idx < 3 * B_ * T_) {
            int s   = idx / (B_ * T_);
            int rem = idx - s * (B_ * T_);
            int b   = rem / T_;
            int t   = rem - b * T_;

            int hw = (s == 0) ? 80 : ((s == 1) ? 40 : 20);
            const float* pred = (s == 0) ? pr3 : ((s == 1) ? pr4 : pr5);
            int a0 = 3 * s;

            const float* tg = targets + (size_t)(b * T_ + t) * 5;
            float clsf = tg[0], tx = tg[1], ty = tg[2], tw = tg[3], th = tg[4];

            bool valid = (tx >= 0.f) && (tx <= 1.f) && (ty >= 0.f) && (ty <= 1.f) &&
                         (tw > 0.f)  && (tw <= 1.f) && (th > 0.f)  && (th <= 1.f);

            // best-anchor argmax (first max wins, like jnp.argmax)
            int best = 0; float bestv = -1.f, awb = 0.f, ahb = 0.f;
            #pragma unroll
            for (int a = 0; a < 3; ++a) {
                float aw = anchors[(a0 + a) * 2 + 0] / 640.0f;
                float ah = anchors[(a0 + a) * 2 + 1] / 640.0f;
                float inter = fminf(tw, aw) * fminf(th, ah);
                float uni   = tw * th + aw * ah - inter;
                float r     = inter / (uni + EPS);
                if (r > bestv) { bestv = r; best = a; awb = aw; ahb = ah; }
            }

            int w = hw, h = hw;
            int gxi = (int)floorf(tx * (float)w); gxi = min(max(gxi, 0), w - 1);
            int gyi = (int)floorf(ty * (float)h); gyi = min(max(gyi, 0), h - 1);

            size_t chs = (size_t)h * (size_t)w;
            const float* base = pred + ((size_t)(b * 27 + best * 9) * (size_t)h + (size_t)gyi) * (size_t)w + (size_t)gxi;
            float c0 = base[0 * chs], c1 = base[1 * chs], c2 = base[2 * chs];
            float c3 = base[3 * chs], zc = base[4 * chs];
            float z0 = base[5 * chs], z1 = base[6 * chs];
            float z2 = base[7 * chs], z3 = base[8 * chs];

            float px  = 1.f / (1.f + expf(-c0)) + (float)gxi / (float)w;
            float py  = 1.f / (1.f + expf(-c1)) + (float)gyi / (float)h;
            float pw_ = expf(c2) * awb;
            float ph_ = expf(c3) * ahb;

            // GIoU
            float x1n = px - pw_ * 0.5f, x1x = px + pw_ * 0.5f;
            float y1n = py - ph_ * 0.5f, y1x = py + ph_ * 0.5f;
            float x2n = tx - tw * 0.5f,  x2x = tx + tw * 0.5f;
            float y2n = ty - th * 0.5f,  y2x = ty + th * 0.5f;
            float iw = fmaxf(fminf(x1x, x2x) - fmaxf(x1n, x2n), 0.f);
            float ih = fmaxf(fminf(y1x, y2x) - fmaxf(y1n, y2n), 0.f);
            float inter = iw * ih;
            float uni = pw_ * ph_ + tw * th - inter + EPS;
            float iou = inter / uni;
            float ew = fmaxf(x1x, x2x) - fminf(x1n, x2n);
            float eh = fmaxf(y1x, y2x) - fminf(y1n, y2n);
            float enclose = ew * eh + EPS;
            float giou = iou - (enclose - uni) / enclose;

            int cid = (int)clsf;
            float mask = (valid && (cid < NUM_CLASSES)) ? 1.f : 0.f;

            v0 = mask * (1.f - giou);

            float sbce = softplusf(z0) + softplusf(z1) + softplusf(z2) + softplusf(z3);
            float zsel = (cid == 0) ? z0 : (cid == 1) ? z1 : (cid == 2) ? z2 : (cid == 3) ? z3 : 0.f;
            v1 = mask * 0.25f * (sbce - zsel);

            float conf_t = fminf(fmaxf(giou, 0.f), 1.f);
            v2 = mask * (softplusf(zc) - conf_t * zc);

            v3 = valid ? 1.f : 0.f;
        }
    } else {
        // ------- negative conf: 4 elements per thread, int4 index load ---
        int gi = (bid - NPOSB) * 256 + tid;       // [0, 24064)
        if (gi < 24000) {
            int e0  = gi * 4;                     // first of 4 consecutive elems
            int s   = e0 / (B_ * NNEG);           // same s for all 4 (32000 % 4 == 0)
            int rem = e0 - s * (B_ * NNEG);
            int b   = rem / NNEG;                 // same b for all 4 (500 % 4 == 0)
            int j   = rem - b * NNEG;

            int hw = (s == 0) ? 80 : ((s == 1) ? 40 : 20);
            int chs = hw * hw;
            const float* pred = (s == 0) ? pr3 : ((s == 1) ? pr4 : pr5);
            const int* nix = (s == 0) ? ng3 : ((s == 1) ? ng4 : ng5);

            int4 id4 = *(const int4*)(nix + b * NNEG + j);   // coalesced 16B

            const float* pb = pred + (size_t)(b * 27) * (size_t)chs;
            int ia0 = id4.x / chs, ia1 = id4.y / chs, ia2 = id4.z / chs, ia3 = id4.w / chs;
            // 4 independent gathers (max MLP)
            float za = pb[(size_t)(ia0 * 9 + 4) * (size_t)chs + (id4.x - ia0 * chs)];
            float zb = pb[(size_t)(ia1 * 9 + 4) * (size_t)chs + (id4.y - ia1 * chs)];
            float zc2 = pb[(size_t)(ia2 * 9 + 4) * (size_t)chs + (id4.z - ia2 * chs)];
            float zd = pb[(size_t)(ia3 * 9 + 4) * (size_t)chs + (id4.w - ia3 * chs)];
            v4 = softplusf(za) + softplusf(zb) + softplusf(zc2) + softplusf(zd);
        }
    }

    // -------- per-block tree reduce of the 5 partials (deterministic) ----
    sred[0][tid] = v0; sred[1][tid] = v1; sred[2][tid] = v2;
    sred[3][tid] = v3; sred[4][tid] = v4;
    __syncthreads();
    for (int s = 128; s > 0; s >>= 1) {
        if (tid < s) {
            sred[0][tid] += sred[0][tid + s];
            sred[1][tid] += sred[1][tid + s];
            sred[2][tid] += sred[2][tid + s];
            sred[3][tid] += sred[3][tid + s];
            sred[4][tid] += sred[4][tid + s];
        }
        __syncthreads();
    }
    if (tid == 0) {
        float* slot = ws + (size_t)bid * WSTRIDE;
        slot[0] = sred[0][0]; slot[1] = sred[1][0]; slot[2] = sred[2][0];
        slot[3] = sred[3][0]; slot[4] = sred[4][0];
        __hip_atomic_store((unsigned int*)(slot + 5), MAGIC,
                           __ATOMIC_RELEASE, __HIP_MEMORY_SCOPE_AGENT);
    }

    if (bid != 0) return;

    // -------- block 0: spin-acquire all partials, finalize ---------------
    // Safe: 132 blocks all co-resident (<< capacity) and workers never wait.
    float a0 = 0.f, a1 = 0.f, a2 = 0.f, a3 = 0.f, a4 = 0.f;
    {
        int i = tid;
        if (i < NBLK) {
            unsigned int* flag = (unsigned int*)(ws + (size_t)i * WSTRIDE + 5);
            while (__hip_atomic_load(flag, __ATOMIC_ACQUIRE,
                                     __HIP_MEMORY_SCOPE_AGENT) != MAGIC) {
                __builtin_amdgcn_s_sleep(1);
            }
            const float* slot = ws + (size_t)i * WSTRIDE;
            a0 += slot[0]; a1 += slot[1]; a2 += slot[2];
            a3 += slot[3]; a4 += slot[4];
            *flag = 0u;   // reset for next replay (0 != MAGIC, overwritten next call)
        }
    }
    __syncthreads();   // sred free for reuse after this
    sred[0][tid] = a0; sred[1][tid] = a1; sred[2][tid] = a2;
    sred[3][tid] = a3; sred[4][tid] = a4;
    __syncthreads();
    for (int s = 128; s > 0; s >>= 1) {
        if (tid < s) {
            sred[0][tid] += sred[0][tid + s];
            sred[1][tid] += sred[1][tid + s];
            sred[2][tid] += sred[2][tid + s];
            sred[3][tid] += sred[3][tid + s];
            sred[4][tid] += sred[4][tid + s];
        }
        __syncthreads();
    }
    if (tid == 0) {
        float box = sred[0][0], cls = sred[1][0], conf = sred[2][0];
        float nn = sred[3][0], negsum = sred[4][0];
        float denom = fmaxf(nn, 1.f);
        if (nn > 0.f) { box /= denom; cls /= denom; conf /= denom; }
        // per scale: 0.5 * sum_b(mean_j softplus) / (B*NNEG); same factor
        // for all 3 scales -> folded.
        float neg = 0.5f * negsum / ((float)NNEG * (float)(B_ * NNEG));
        conf += neg;
        out[0] = box + cls + conf; out[1] = box; out[2] = cls; out[3] = conf;
    }
}

extern "C" void kernel_launch(void* const* d_in, const int* in_sizes, int n_in,
                              void* d_out, int out_size, void* d_ws, size_t ws_size,
                              hipStream_t stream) {
    const float* p3      = (const float*)d_in[0];
    const float* p4      = (const float*)d_in[1];
    const float* p5      = (const float*)d_in[2];
    const float* targets = (const float*)d_in[3];
    const float* anchors = (const float*)d_in[4];
    const int*   ng3     = (const int*)d_in[5];
    const int*   ng4     = (const int*)d_in[6];
    const int*   ng5     = (const int*)d_in[7];

    yolo_fused<<<dim3(NBLK), dim3(256), 0, stream>>>(
        p3, p4, p5, targets, anchors, ng3, ng4, ng5,
        (float*)d_ws, (float*)d_out);
}